// Round 2
// baseline (1195.921 us; speedup 1.0000x reference)
//
#include <hip/hip_runtime.h>
#include <hip/hip_bf16.h>

// Problem constants
#define B_ 4
#define DIM_ 256
#define N_ 2048
#define M_ 2048
#define HEADS_ 8
#define DHEAD_ 64
#define DINNER_ 512   // HEADS*DHEAD
#define NEG_MAX (-3.402823466e38f)

// ---------------------------------------------------------------------------
// Kernel 1: per-column RMS scale.  x:[B,C,NN] fp32 -> scale[b,n] =
// sqrt(C) / max(||x[:,n]||, eps).  grid (NN/64, B), block (64,4)
// ---------------------------------------------------------------------------
__global__ __launch_bounds__(256) void colnorm_kernel(
    const float* __restrict__ x, float* __restrict__ scale, int C, int NN,
    float sqrtC) {
  int b = blockIdx.y;
  int tx = threadIdx.x, ty = threadIdx.y;
  int n = blockIdx.x * 64 + tx;
  const float* xb = x + (size_t)b * C * NN;

  float ssq = 0.f;
  for (int c = ty; c < C; c += 4) {
    float v = xb[(size_t)c * NN + n];
    ssq += v * v;
  }
  __shared__ float red[4][64];
  red[ty][tx] = ssq;
  __syncthreads();
  if (ty == 0) {
    float s = red[0][tx] + red[1][tx] + red[2][tx] + red[3][tx];
    scale[(size_t)b * NN + n] = sqrtC / fmaxf(sqrtf(s), 1e-12f);
  }
}

// ---------------------------------------------------------------------------
// Kernel 2: channel GEMM with optional fused RMSNorm.
// HAS_NORM: Y[b,o,n] = scale[b,n] * sum_c (W[o,c]*gamma[c]) * X[b,c,n]
// else:     Y[b,o,n] = sum_c W[o,c] * X[b,c,n]
// W fp32 [O,C], X fp32 [B,C,NN].  grid (NN/64, O/32, B), block (64,4).
// Each thread: 8 outputs (o = o0 + ty*8 + r) for one n.
// ---------------------------------------------------------------------------
template <bool HAS_NORM>
__global__ __launch_bounds__(256) void gemm_kernel(
    const float* __restrict__ W, const float* __restrict__ gamma,
    const float* __restrict__ X, const float* __restrict__ scale,
    float* __restrict__ Y, int O, int C, int NN) {
  int b = blockIdx.z;
  int n0 = blockIdx.x * 64;
  int o0 = blockIdx.y * 32;
  int tx = threadIdx.x, ty = threadIdx.y;
  int tid = ty * 64 + tx;

  __shared__ float Wl[32][33];
  __shared__ __align__(16) float Xl[32][64];
  float acc[8] = {0.f, 0.f, 0.f, 0.f, 0.f, 0.f, 0.f, 0.f};
  const float* Xb = X + (size_t)b * C * NN;

  for (int c0 = 0; c0 < C; c0 += 32) {
    for (int idx = tid; idx < 32 * 32; idx += 256) {
      int oo = idx >> 5, cc = idx & 31;
      float w = W[(size_t)(o0 + oo) * C + c0 + cc];
      if (HAS_NORM) w *= gamma[c0 + cc];
      Wl[oo][cc] = w;
    }
    for (int idx = tid; idx < 512; idx += 256) {  // 32x64 as float4
      int cc = idx >> 4, nv = (idx & 15) * 4;
      *(float4*)&Xl[cc][nv] =
          *(const float4*)&Xb[(size_t)(c0 + cc) * NN + n0 + nv];
    }
    __syncthreads();
    for (int cc = 0; cc < 32; ++cc) {
      float xv = Xl[cc][tx];
#pragma unroll
      for (int r = 0; r < 8; ++r)
        acc[r] = fmaf(Wl[ty * 8 + r][cc], xv, acc[r]);
    }
    __syncthreads();
  }
  float sc = HAS_NORM ? scale[(size_t)b * NN + n0 + tx] : 1.0f;
  for (int r = 0; r < 8; ++r) {
    int o = o0 + ty * 8 + r;
    Y[((size_t)b * O + o) * NN + n0 + tx] = acc[r] * sc;
  }
}

// ---------------------------------------------------------------------------
// Kernel 3: L2-distance attention, flash-style.
// q:[B,512,N] fp32, kv:[B,1024,M] fp32, mask:[B,M] int -> out:[B,512,N] fp32
// grid (N/64, HEADS, B), block 256.
// Block handles a 64-row query tile for one (b,h); loops over 32 j-chunks
// of 64.  4x4 register micro-tiles for both QK^T and PV.
// ---------------------------------------------------------------------------
__global__ __launch_bounds__(256) void attn_kernel(
    const float* __restrict__ q, const float* __restrict__ kv,
    const int* __restrict__ mask, float* __restrict__ out) {
  const int i0 = blockIdx.x * 64;
  const int h = blockIdx.y;
  const int b = blockIdx.z;
  const int tid = threadIdx.x;

  const int r4 = (tid >> 4) * 4;  // i-block (rows) for this thread
  const int c4 = (tid & 15) * 4;  // j-block in sim phase / d-block in pv phase

  __shared__ __align__(16) float q_lds[64][68];  // [d][i]; reused as o[d][i]
  __shared__ __align__(16) float k_lds[64][68];  // [d][j]
  __shared__ __align__(16) float v_lds[64][68];  // [j][d]
  __shared__ __align__(16) float p_lds[64][68];  // [j][i]
  __shared__ float q2_lds[64], k2_lds[64], alpha_lds[64], l_lds[64];
  __shared__ int msk_lds[64];

  const float* qbase = q + ((size_t)b * DINNER_ + h * DHEAD_) * (size_t)N_;
  const float* kbase = kv + ((size_t)b * 2 * DINNER_ + h * DHEAD_) * (size_t)M_;
  const float* vbase =
      kv + ((size_t)b * 2 * DINNER_ + DINNER_ + h * DHEAD_) * (size_t)M_;
  const int* maskb = mask + (size_t)b * M_;

  // stage Q tile: q_lds[d][i]
  for (int idx = tid; idx < 1024; idx += 256) {
    int d = idx >> 4, iv = (idx & 15) * 4;
    *(float4*)&q_lds[d][iv] = *(const float4*)&qbase[(size_t)d * N_ + i0 + iv];
  }
  __syncthreads();
  if (tid < 64) {
    float s = 0.f;
    for (int d = 0; d < 64; ++d) {
      float v = q_lds[d][tid];
      s += v * v;
    }
    q2_lds[tid] = s;
  }

  float acc[4][4] = {};
  float m_row = NEG_MAX, l_row = 0.f;  // valid for tid<64 only

  for (int j0 = 0; j0 < M_; j0 += 64) {
    __syncthreads();  // previous pv done before restaging k/v
    for (int idx = tid; idx < 1024; idx += 256) {
      int d = idx >> 4, jv = (idx & 15) * 4;
      *(float4*)&k_lds[d][jv] =
          *(const float4*)&kbase[(size_t)d * M_ + j0 + jv];
      float4 t = *(const float4*)&vbase[(size_t)d * M_ + j0 + jv];
      v_lds[jv + 0][d] = t.x;
      v_lds[jv + 1][d] = t.y;
      v_lds[jv + 2][d] = t.z;
      v_lds[jv + 3][d] = t.w;
    }
    if (tid < 64) msk_lds[tid] = maskb[j0 + tid];
    __syncthreads();
    if (tid < 64) {
      float s = 0.f;
      for (int d = 0; d < 64; ++d) {
        float v = k_lds[d][tid];
        s += v * v;
      }
      k2_lds[tid] = s;
    }
    __syncthreads();

    // sim phase: 4x4 micro-tile per thread: rows r4.., cols (j) c4..
    float s[4][4] = {};
    for (int d = 0; d < 64; ++d) {
      float4 q4 = *(const float4*)&q_lds[d][r4];
      float4 k4 = *(const float4*)&k_lds[d][c4];
      float qa[4] = {q4.x, q4.y, q4.z, q4.w};
      float kb[4] = {k4.x, k4.y, k4.z, k4.w};
#pragma unroll
      for (int a = 0; a < 4; ++a)
#pragma unroll
        for (int c = 0; c < 4; ++c) s[a][c] = fmaf(qa[a], kb[c], s[a][c]);
    }
#pragma unroll
    for (int c = 0; c < 4; ++c) {
      float k2 = k2_lds[c4 + c];
      int mv = msk_lds[c4 + c];
      float out4[4];
#pragma unroll
      for (int a = 0; a < 4; ++a) {
        float d2 = q2_lds[r4 + a] + k2 - 2.f * s[a][c];
        d2 = fmaxf(d2, 0.f);
        float dist = sqrtf(fmaxf(d2, 1e-12f));
        float sim = -dist * 0.125f;  // DHEAD^-0.5
        out4[a] = (mv == 0) ? NEG_MAX : sim;
      }
      *(float4*)&p_lds[c4 + c][r4] =
          make_float4(out4[0], out4[1], out4[2], out4[3]);
    }
    __syncthreads();

    // online softmax, one thread per row
    if (tid < 64) {
      const int i = tid;
      float mc = NEG_MAX;
      for (int j = 0; j < 64; ++j) mc = fmaxf(mc, p_lds[j][i]);
      float m_new = fmaxf(m_row, mc);
      float alpha = expf(m_row - m_new);
      float lsum = 0.f;
      for (int j = 0; j < 64; ++j) {
        float pv = expf(p_lds[j][i] - m_new);
        p_lds[j][i] = pv;
        lsum += pv;
      }
      l_row = l_row * alpha + lsum;
      m_row = m_new;
      alpha_lds[i] = alpha;
    }
    __syncthreads();

    // pv phase: acc[a][c] over rows r4.., dims c4..
    float al[4];
#pragma unroll
    for (int a = 0; a < 4; ++a) al[a] = alpha_lds[r4 + a];
#pragma unroll
    for (int a = 0; a < 4; ++a)
#pragma unroll
      for (int c = 0; c < 4; ++c) acc[a][c] *= al[a];
    for (int j = 0; j < 64; ++j) {
      float4 p4 = *(const float4*)&p_lds[j][r4];
      float4 v4 = *(const float4*)&v_lds[j][c4];
      float pa[4] = {p4.x, p4.y, p4.z, p4.w};
      float vb[4] = {v4.x, v4.y, v4.z, v4.w};
#pragma unroll
      for (int a = 0; a < 4; ++a)
#pragma unroll
        for (int c = 0; c < 4; ++c) acc[a][c] = fmaf(pa[a], vb[c], acc[a][c]);
    }
  }

  if (tid < 64) l_lds[tid] = l_row;
  __syncthreads();
  // write o into q_lds[d][i], normalized
  {
    float rl[4];
#pragma unroll
    for (int a = 0; a < 4; ++a) rl[a] = 1.0f / l_lds[r4 + a];
#pragma unroll
    for (int a = 0; a < 4; ++a)
#pragma unroll
      for (int c = 0; c < 4; ++c) q_lds[c4 + c][r4 + a] = acc[a][c] * rl[a];
  }
  __syncthreads();
  float* obase = out + ((size_t)b * DINNER_ + h * DHEAD_) * (size_t)N_;
  for (int idx = tid; idx < 1024; idx += 256) {
    int d = idx >> 4, iv = (idx & 15) * 4;
    *(float4*)&obase[(size_t)d * N_ + i0 + iv] = *(const float4*)&q_lds[d][iv];
  }
}

// ---------------------------------------------------------------------------
extern "C" void kernel_launch(void* const* d_in, const int* in_sizes, int n_in,
                              void* d_out, int out_size, void* d_ws,
                              size_t ws_size, hipStream_t stream) {
  const float* fmap = (const float*)d_in[0];
  const float* context = (const float*)d_in[1];
  const int* mask = (const int*)d_in[2];
  const float* gamma = (const float*)d_in[3];
  const float* gamma_ctx = (const float*)d_in[4];
  const float* Wq = (const float*)d_in[5];
  const float* Wkv = (const float*)d_in[6];
  const float* Wout = (const float*)d_in[7];
  float* out = (float*)d_out;

  float* ws = (float*)d_ws;
  float* scale_f = ws;                   // 4*2048 = 8192 f
  float* scale_c = scale_f + 8192;       // 8192 f
  float* qbuf = scale_c + 8192;          // 4*512*2048  = 4,194,304 f
  float* kvbuf = qbuf + 4194304;         // 4*1024*2048 = 8,388,608 f
  float* attn_o = kvbuf + 8388608;       // 4,194,304 f   (~64 MB total)

  dim3 blk(64, 4);
  colnorm_kernel<<<dim3(N_ / 64, B_), blk, 0, stream>>>(fmap, scale_f, DIM_,
                                                        N_, 16.0f);
  colnorm_kernel<<<dim3(M_ / 64, B_), blk, 0, stream>>>(context, scale_c, DIM_,
                                                        M_, 16.0f);
  gemm_kernel<true><<<dim3(N_ / 64, DINNER_ / 32, B_), blk, 0, stream>>>(
      Wq, gamma, fmap, scale_f, qbuf, DINNER_, DIM_, N_);
  gemm_kernel<true><<<dim3(M_ / 64, 2 * DINNER_ / 32, B_), blk, 0, stream>>>(
      Wkv, gamma_ctx, context, scale_c, kvbuf, 2 * DINNER_, DIM_, M_);
  attn_kernel<<<dim3(N_ / 64, HEADS_, B_), 256, 0, stream>>>(qbuf, kvbuf, mask,
                                                             attn_o);
  gemm_kernel<false><<<dim3(N_ / 64, DIM_ / 32, B_), blk, 0, stream>>>(
      Wout, nullptr, attn_o, nullptr, out, DIM_, DINNER_, N_);
}

// Round 3
// 862.802 us; speedup vs baseline: 1.3861x; 1.3861x over previous
//
#include <hip/hip_runtime.h>
#include <hip/hip_bf16.h>

// Problem constants
#define B_ 4
#define DIM_ 256
#define N_ 2048
#define M_ 2048
#define HEADS_ 8
#define DHEAD_ 64
#define DINNER_ 512   // HEADS*DHEAD
#define NEG_MAX (-3.402823466e38f)

typedef __attribute__((ext_vector_type(8))) short short8;
typedef __attribute__((ext_vector_type(4))) short short4v;
typedef __attribute__((ext_vector_type(4))) float floatx4;

__device__ inline short bf16_hi_bits(float x) {  // RNE f32->bf16, bit form
  unsigned u = __float_as_uint(x);
  unsigned r = (u + 0x7fffu + ((u >> 16) & 1u)) >> 16;
  return (short)r;
}
__device__ inline float bf16_bits_f32(short b) {
  return __uint_as_float(((unsigned)(unsigned short)b) << 16);
}

// ---------------------------------------------------------------------------
// Kernel 1: per-column RMS scale.  scale[b,n] = sqrt(C)/max(||x[:,n]||,eps)
// ---------------------------------------------------------------------------
__global__ __launch_bounds__(256) void colnorm_kernel(
    const float* __restrict__ x, float* __restrict__ scale, int C, int NN,
    float sqrtC) {
  int b = blockIdx.y;
  int tx = threadIdx.x, ty = threadIdx.y;
  int n = blockIdx.x * 64 + tx;
  const float* xb = x + (size_t)b * C * NN;

  float ssq = 0.f;
  for (int c = ty; c < C; c += 4) {
    float v = xb[(size_t)c * NN + n];
    ssq += v * v;
  }
  __shared__ float red[4][64];
  red[ty][tx] = ssq;
  __syncthreads();
  if (ty == 0) {
    float s = red[0][tx] + red[1][tx] + red[2][tx] + red[3][tx];
    scale[(size_t)b * NN + n] = sqrtC / fmaxf(sqrtf(s), 1e-12f);
  }
}

// ---------------------------------------------------------------------------
// Kernel 2: channel GEMM with optional fused RMSNorm.
// ---------------------------------------------------------------------------
template <bool HAS_NORM>
__global__ __launch_bounds__(256) void gemm_kernel(
    const float* __restrict__ W, const float* __restrict__ gamma,
    const float* __restrict__ X, const float* __restrict__ scale,
    float* __restrict__ Y, int O, int C, int NN) {
  int b = blockIdx.z;
  int n0 = blockIdx.x * 64;
  int o0 = blockIdx.y * 32;
  int tx = threadIdx.x, ty = threadIdx.y;
  int tid = ty * 64 + tx;

  __shared__ float Wl[32][33];
  __shared__ __align__(16) float Xl[32][64];
  float acc[8] = {0.f, 0.f, 0.f, 0.f, 0.f, 0.f, 0.f, 0.f};
  const float* Xb = X + (size_t)b * C * NN;

  for (int c0 = 0; c0 < C; c0 += 32) {
    for (int idx = tid; idx < 32 * 32; idx += 256) {
      int oo = idx >> 5, cc = idx & 31;
      float w = W[(size_t)(o0 + oo) * C + c0 + cc];
      if (HAS_NORM) w *= gamma[c0 + cc];
      Wl[oo][cc] = w;
    }
    for (int idx = tid; idx < 512; idx += 256) {
      int cc = idx >> 4, nv = (idx & 15) * 4;
      *(float4*)&Xl[cc][nv] =
          *(const float4*)&Xb[(size_t)(c0 + cc) * NN + n0 + nv];
    }
    __syncthreads();
    for (int cc = 0; cc < 32; ++cc) {
      float xv = Xl[cc][tx];
#pragma unroll
      for (int r = 0; r < 8; ++r)
        acc[r] = fmaf(Wl[ty * 8 + r][cc], xv, acc[r]);
    }
    __syncthreads();
  }
  float sc = HAS_NORM ? scale[(size_t)b * NN + n0 + tx] : 1.0f;
  for (int r = 0; r < 8; ++r) {
    int o = o0 + ty * 8 + r;
    Y[((size_t)b * O + o) * NN + n0 + tx] = acc[r] * sc;
  }
}

// ---------------------------------------------------------------------------
// Kernel 3: L2-distance attention, flash-style, MFMA 16x16x32 bf16.
// QK^T in split precision (hi/lo bf16, 3 MFMAs ~ fp32); PV in bf16.
// Block: 256 thr = 4 waves; one (b,h), 64 query rows (16 per wave).
// Per 64-j chunk: K staged fp32 [d][j] (pad 66), V bf16 [dd][j] (pad 68),
// P transposed C->A layout through wave-private LDS rows.
// ---------------------------------------------------------------------------
__global__ __launch_bounds__(256, 4) void attn_mfma_kernel(
    const float* __restrict__ q, const float* __restrict__ kv,
    const int* __restrict__ mask, float* __restrict__ out) {
  const int i0 = blockIdx.x * 64;
  const int h = blockIdx.y;
  const int b = blockIdx.z;
  const int tid = threadIdx.x;
  const int w = tid >> 6, l = tid & 63, quad = l >> 4, l15 = l & 15;

  __shared__ union U {
    float k_f[64][66];  // K chunk fp32, [d][j]
    float o_f[64][68];  // epilogue: O transpose, [dd][i_local]
  } u;
  __shared__ __align__(16) short v_s[64][68];  // V bf16 [dd][j]
  __shared__ __align__(16) short p_s[64][72];  // P bf16 [i_local][j]
  __shared__ float k2p[4][64];                 // k2 partial sums

  const float* qb = q + ((size_t)b * DINNER_ + h * DHEAD_) * (size_t)N_;
  const float* kb = kv + ((size_t)b * 2 * DINNER_ + h * DHEAD_) * (size_t)M_;
  const float* vb =
      kv + ((size_t)b * 2 * DINNER_ + DINNER_ + h * DHEAD_) * (size_t)M_;
  const int* mb = mask + (size_t)b * M_;

  // ---- Q fragments (A-layout: m=l15, k=quad*8+jj+32*kt), hi/lo split ----
  short8 qhi[2], qlo[2];
  float q2p = 0.f;
  const int irow = i0 + 16 * w + l15;
#pragma unroll
  for (int kt = 0; kt < 2; ++kt)
#pragma unroll
    for (int jj = 0; jj < 8; ++jj) {
      int d = 32 * kt + 8 * quad + jj;
      float x = qb[(size_t)d * N_ + irow];
      q2p += x * x;
      short hb = bf16_hi_bits(x);
      qhi[kt][jj] = hb;
      qlo[kt][jj] = bf16_hi_bits(x - bf16_bits_f32(hb));
    }
  float q2row = q2p + __shfl_xor(q2p, 16);
  q2row += __shfl_xor(q2row, 32);
  // move q2 from row=l15 layout to C-layout rows (4*quad+r)
  float q2c[4];
#pragma unroll
  for (int r = 0; r < 4; ++r) q2c[r] = __shfl(q2row, 4 * quad + r);

  floatx4 accO[4];  // [ddt] C-layout accumulators
#pragma unroll
  for (int dt = 0; dt < 4; ++dt)
#pragma unroll
    for (int r = 0; r < 4; ++r) accO[dt][r] = 0.f;
  float mrow[4], lrow[4];
#pragma unroll
  for (int r = 0; r < 4; ++r) {
    mrow[r] = NEG_MAX;
    lrow[r] = 0.f;
  }

  for (int j0 = 0; j0 < M_; j0 += 64) {
    __syncthreads();  // prior iteration's LDS reads complete
    // ---- stage K (fp32) and V (bf16), coalesced ----
    {
      int dt = tid >> 4, j4 = (tid & 15) * 4;
#pragma unroll
      for (int iter = 0; iter < 4; ++iter) {
        int d = iter * 16 + dt;
        float4 kx = *(const float4*)&kb[(size_t)d * M_ + j0 + j4];
        // rows are 264 B apart (not 16B-multiple): store as 2x float2
        float2 kx0 = make_float2(kx.x, kx.y), kx1 = make_float2(kx.z, kx.w);
        *(float2*)&u.k_f[d][j4] = kx0;
        *(float2*)&u.k_f[d][j4 + 2] = kx1;
        float4 vx = *(const float4*)&vb[(size_t)d * M_ + j0 + j4];
        short4v vs;
        vs[0] = bf16_hi_bits(vx.x);
        vs[1] = bf16_hi_bits(vx.y);
        vs[2] = bf16_hi_bits(vx.z);
        vs[3] = bf16_hi_bits(vx.w);
        *(short4v*)&v_s[d][j4] = vs;
      }
    }
    // ---- k2 partials (from global, L2-warm) ----
    {
      int jj = tid & 63, dg = tid >> 6;
      float s = 0.f;
#pragma unroll
      for (int dd = 0; dd < 16; ++dd) {
        float x = kb[(size_t)(dg * 16 + dd) * M_ + j0 + jj];
        s += x * x;
      }
      k2p[dg][jj] = s;
    }
    __syncthreads();

    // ---- S = Q K^T (split precision) ----
    floatx4 s4[4];
#pragma unroll
    for (int jt = 0; jt < 4; ++jt) {
      floatx4 acc;
#pragma unroll
      for (int r = 0; r < 4; ++r) acc[r] = 0.f;
#pragma unroll
      for (int kt = 0; kt < 2; ++kt) {
        short8 bhi, blo;
#pragma unroll
        for (int jj = 0; jj < 8; ++jj) {
          float x = u.k_f[32 * kt + 8 * quad + jj][16 * jt + l15];
          short hb = bf16_hi_bits(x);
          bhi[jj] = hb;
          blo[jj] = bf16_hi_bits(x - bf16_bits_f32(hb));
        }
        acc = __builtin_amdgcn_mfma_f32_16x16x32_bf16(qlo[kt], bhi, acc, 0, 0, 0);
        acc = __builtin_amdgcn_mfma_f32_16x16x32_bf16(qhi[kt], blo, acc, 0, 0, 0);
        acc = __builtin_amdgcn_mfma_f32_16x16x32_bf16(qhi[kt], bhi, acc, 0, 0, 0);
      }
      s4[jt] = acc;
    }

    // ---- sim = -sqrt(max(q2+k2-2qk,0)) * d^-0.5, masked ----
#pragma unroll
    for (int jt = 0; jt < 4; ++jt) {
      int col = 16 * jt + l15;
      float k2v = k2p[0][col] + k2p[1][col] + k2p[2][col] + k2p[3][col];
      int mv = mb[j0 + col];
#pragma unroll
      for (int r = 0; r < 4; ++r) {
        float d2 = fmaxf(fmaf(-2.f, s4[jt][r], q2c[r] + k2v), 0.f);
        float sim = -0.125f * sqrtf(fmaxf(d2, 1e-12f));
        s4[jt][r] = mv ? sim : NEG_MAX;
      }
    }

    // ---- online softmax (rows r=4*quad+reg, cols over l15 x jt) ----
    float rm[4];
#pragma unroll
    for (int r = 0; r < 4; ++r)
      rm[r] = fmaxf(fmaxf(s4[0][r], s4[1][r]), fmaxf(s4[2][r], s4[3][r]));
#pragma unroll
    for (int off = 1; off < 16; off <<= 1)
#pragma unroll
      for (int r = 0; r < 4; ++r) rm[r] = fmaxf(rm[r], __shfl_xor(rm[r], off));

    float alpha[4], lsum[4];
#pragma unroll
    for (int r = 0; r < 4; ++r) {
      float mn = fmaxf(mrow[r], rm[r]);
      alpha[r] = __expf(mrow[r] - mn);
      mrow[r] = mn;
      lsum[r] = 0.f;
    }
#pragma unroll
    for (int jt = 0; jt < 4; ++jt)
#pragma unroll
      for (int r = 0; r < 4; ++r) {
        float p = __expf(s4[jt][r] - mrow[r]);
        lsum[r] += p;
        p_s[16 * w + 4 * quad + r][16 * jt + l15] = bf16_hi_bits(p);
      }
#pragma unroll
    for (int off = 1; off < 16; off <<= 1)
#pragma unroll
      for (int r = 0; r < 4; ++r) lsum[r] += __shfl_xor(lsum[r], off);
#pragma unroll
    for (int r = 0; r < 4; ++r) lrow[r] = lrow[r] * alpha[r] + lsum[r];

#pragma unroll
    for (int dt = 0; dt < 4; ++dt)
#pragma unroll
      for (int r = 0; r < 4; ++r) accO[dt][r] *= alpha[r];

    // ---- O += P V (P rows are wave-private; no barrier needed) ----
    short8 pa[2];
#pragma unroll
    for (int kt = 0; kt < 2; ++kt)
      pa[kt] = *(const short8*)&p_s[16 * w + l15][32 * kt + 8 * quad];
#pragma unroll
    for (int dt = 0; dt < 4; ++dt)
#pragma unroll
      for (int kt = 0; kt < 2; ++kt) {
        short4v v0 = *(const short4v*)&v_s[16 * dt + l15][32 * kt + 8 * quad];
        short4v v1 =
            *(const short4v*)&v_s[16 * dt + l15][32 * kt + 8 * quad + 4];
        short8 bv;
#pragma unroll
        for (int e = 0; e < 4; ++e) {
          bv[e] = v0[e];
          bv[e + 4] = v1[e];
        }
        accO[dt] =
            __builtin_amdgcn_mfma_f32_16x16x32_bf16(pa[kt], bv, accO[dt], 0, 0, 0);
      }
  }

  __syncthreads();  // done reading k_f/v_s; reuse union as O transpose
#pragma unroll
  for (int dt = 0; dt < 4; ++dt)
#pragma unroll
    for (int r = 0; r < 4; ++r)
      u.o_f[16 * dt + l15][16 * w + 4 * quad + r] = accO[dt][r] / lrow[r];
  __syncthreads();
  float* ob = out + ((size_t)b * DINNER_ + h * DHEAD_) * (size_t)N_;
  {
    int dt = tid >> 4, i4 = (tid & 15) * 4;
#pragma unroll
    for (int iter = 0; iter < 4; ++iter) {
      int dd = iter * 16 + dt;
      *(float4*)&ob[(size_t)dd * N_ + i0 + i4] = *(const float4*)&u.o_f[dd][i4];
    }
  }
}

// ---------------------------------------------------------------------------
extern "C" void kernel_launch(void* const* d_in, const int* in_sizes, int n_in,
                              void* d_out, int out_size, void* d_ws,
                              size_t ws_size, hipStream_t stream) {
  const float* fmap = (const float*)d_in[0];
  const float* context = (const float*)d_in[1];
  const int* mask = (const int*)d_in[2];
  const float* gamma = (const float*)d_in[3];
  const float* gamma_ctx = (const float*)d_in[4];
  const float* Wq = (const float*)d_in[5];
  const float* Wkv = (const float*)d_in[6];
  const float* Wout = (const float*)d_in[7];
  float* out = (float*)d_out;

  float* ws = (float*)d_ws;
  float* scale_f = ws;                   // 8192 f
  float* scale_c = scale_f + 8192;       // 8192 f
  float* qbuf = scale_c + 8192;          // 4,194,304 f
  float* kvbuf = qbuf + 4194304;         // 8,388,608 f
  float* attn_o = kvbuf + 8388608;       // 4,194,304 f

  dim3 blk(64, 4);
  colnorm_kernel<<<dim3(N_ / 64, B_), blk, 0, stream>>>(fmap, scale_f, DIM_,
                                                        N_, 16.0f);
  colnorm_kernel<<<dim3(M_ / 64, B_), blk, 0, stream>>>(context, scale_c, DIM_,
                                                        M_, 16.0f);
  gemm_kernel<true><<<dim3(N_ / 64, DINNER_ / 32, B_), blk, 0, stream>>>(
      Wq, gamma, fmap, scale_f, qbuf, DINNER_, DIM_, N_);
  gemm_kernel<true><<<dim3(M_ / 64, 2 * DINNER_ / 32, B_), blk, 0, stream>>>(
      Wkv, gamma_ctx, context, scale_c, kvbuf, 2 * DINNER_, DIM_, M_);
  attn_mfma_kernel<<<dim3(N_ / 64, HEADS_, B_), 256, 0, stream>>>(
      qbuf, kvbuf, mask, attn_o);
  gemm_kernel<false><<<dim3(N_ / 64, DIM_ / 32, B_), blk, 0, stream>>>(
      Wout, nullptr, attn_o, nullptr, out, DIM_, DINNER_, N_);
}

// Round 4
// 449.288 us; speedup vs baseline: 2.6618x; 1.9204x over previous
//
#include <hip/hip_runtime.h>
#include <hip/hip_bf16.h>

// Problem constants
#define B_ 4
#define DIM_ 256
#define N_ 2048
#define M_ 2048
#define HEADS_ 8
#define DHEAD_ 64
#define DINNER_ 512
#define NEG_MAX (-3.402823466e38f)

typedef __attribute__((ext_vector_type(8))) short short8;
typedef __attribute__((ext_vector_type(4))) short short4v;
typedef __attribute__((ext_vector_type(4))) float floatx4;

__device__ inline short bf16r(float x) {  // RNE f32->bf16 (bit form)
  unsigned u = __float_as_uint(x);
  unsigned r = (u + 0x7fffu + ((u >> 16) & 1u)) >> 16;
  return (short)r;
}
__device__ inline float bf2f(short b) {
  return __uint_as_float(((unsigned)(unsigned short)b) << 16);
}

// ---------------------------------------------------------------------------
// Kernel 1: channel RMSNorm -> bf16 transposed.  x:[b,C,NN] fp32 ->
// xt[b,n,C] bf16 with xt = x * sqrt(C)/max(||x[:,n]||,eps).  gamma NOT here
// (folded into W at GEMM staging).  grid (NN/64, B), block (64,4).
// ---------------------------------------------------------------------------
__global__ __launch_bounds__(256) void colnorm_t_kernel(
    const float* __restrict__ x, short* __restrict__ xt, int C, int NN,
    float sqrtC) {
  int b = blockIdx.y;
  int tx = threadIdx.x, ty = threadIdx.y;
  int n = blockIdx.x * 64 + tx;
  const float* xb = x + (size_t)b * C * NN;

  float ssq = 0.f;
  for (int c = ty; c < C; c += 4) {
    float v = xb[(size_t)c * NN + n];
    ssq += v * v;
  }
  __shared__ float red[4][64];
  red[ty][tx] = ssq;
  __syncthreads();
  if (ty == 0) {
    float s = red[0][tx] + red[1][tx] + red[2][tx] + red[3][tx];
    red[0][tx] = sqrtC / fmaxf(sqrtf(s), 1e-12f);
  }
  __syncthreads();
  float scale = red[0][tx];
  short* xrow = xt + ((size_t)b * NN + n) * C;
  for (int c = ty; c < C; c += 4) xrow[c] = bf16r(xb[(size_t)c * NN + n] * scale);
}

// ---------------------------------------------------------------------------
// Kernel 2: MFMA GEMM.  Y[b,o,n] = sum_c (W[o,c]*gamma[c]) * Xt[b,n,c]
// W fp32 [O][C] split hi/lo in LDS (2 MFMAs -> ~fp32 weights); Xt bf16.
// Block tile 128o x 128n, 4 waves as 2x2, wave tile 64x64 (4x4 acc).
// EPI: 0 = fp32 [b][O][NN] (out proj), 1 = bf16 [b][n][512] transposed (q/k),
//      2 = kv: o<512 -> EPI1 into Yt, o>=512 -> bf16 [b][ch][NN] into Yv.
// ---------------------------------------------------------------------------
template <int EPI, bool HAS_GAMMA>
__global__ __launch_bounds__(256) void gemm_mfma_kernel(
    const float* __restrict__ W, const float* __restrict__ gamma,
    const short* __restrict__ Xt, float* __restrict__ Yf,
    short* __restrict__ Yt, short* __restrict__ Yv, int C, int O) {
  const int b = blockIdx.z;
  const int n0 = blockIdx.x * 128;
  const int o0 = blockIdx.y * 128;
  const int tid = threadIdx.x;
  const int w = tid >> 6, l = tid & 63, quad = l >> 4, l15 = l & 15;
  const int wo = (w >> 1) * 64, wn = (w & 1) * 64;

  __shared__ __align__(16) short Wa[2][128][40];  // hi/lo planes, pad 40
  __shared__ __align__(16) short Xb[128][40];

  floatx4 acc[4][4];
#pragma unroll
  for (int ot = 0; ot < 4; ++ot)
#pragma unroll
    for (int nt = 0; nt < 4; ++nt)
#pragma unroll
      for (int r = 0; r < 4; ++r) acc[ot][nt][r] = 0.f;

  for (int c0 = 0; c0 < C; c0 += 32) {
    __syncthreads();
    // stage W' (fp32 -> hi/lo bf16)
#pragma unroll
    for (int it = 0; it < 4; ++it) {
      int lin = tid + it * 256;
      int o = lin >> 3, cs = (lin & 7) * 4;
      float4 wv = *(const float4*)&W[(size_t)(o0 + o) * C + c0 + cs];
      if (HAS_GAMMA) {
        float4 g = *(const float4*)&gamma[c0 + cs];
        wv.x *= g.x; wv.y *= g.y; wv.z *= g.z; wv.w *= g.w;
      }
      short4v hi, lo;
      float vv[4] = {wv.x, wv.y, wv.z, wv.w};
#pragma unroll
      for (int e = 0; e < 4; ++e) {
        short hb = bf16r(vv[e]);
        hi[e] = hb;
        lo[e] = bf16r(vv[e] - bf2f(hb));
      }
      *(short4v*)&Wa[0][o][cs] = hi;
      *(short4v*)&Wa[1][o][cs] = lo;
    }
    // stage Xt (bf16 copy)
#pragma unroll
    for (int it = 0; it < 2; ++it) {
      int lin = tid + it * 256;
      int n = lin >> 2, sg = (lin & 3) * 8;
      short8 xv = *(const short8*)&Xt[((size_t)b * 2048 + n0 + n) * C + c0 + sg];
      *(short8*)&Xb[n][sg] = xv;
    }
    __syncthreads();

    short8 ah[4], al[4], bx[4];
#pragma unroll
    for (int ot = 0; ot < 4; ++ot) {
      ah[ot] = *(const short8*)&Wa[0][wo + 16 * ot + l15][8 * quad];
      al[ot] = *(const short8*)&Wa[1][wo + 16 * ot + l15][8 * quad];
    }
#pragma unroll
    for (int nt = 0; nt < 4; ++nt)
      bx[nt] = *(const short8*)&Xb[wn + 16 * nt + l15][8 * quad];
#pragma unroll
    for (int ot = 0; ot < 4; ++ot)
#pragma unroll
      for (int nt = 0; nt < 4; ++nt) {
        acc[ot][nt] =
            __builtin_amdgcn_mfma_f32_16x16x32_bf16(al[ot], bx[nt], acc[ot][nt], 0, 0, 0);
        acc[ot][nt] =
            __builtin_amdgcn_mfma_f32_16x16x32_bf16(ah[ot], bx[nt], acc[ot][nt], 0, 0, 0);
      }
  }

  // epilogue
  if (EPI == 0) {
#pragma unroll
    for (int ot = 0; ot < 4; ++ot)
#pragma unroll
      for (int r = 0; r < 4; ++r) {
        int o = o0 + wo + 16 * ot + 4 * quad + r;
#pragma unroll
        for (int nt = 0; nt < 4; ++nt)
          Yf[((size_t)b * O + o) * 2048 + n0 + wn + 16 * nt + l15] =
              acc[ot][nt][r];
      }
  } else if (EPI == 1 || (EPI == 2 && o0 < 512)) {
#pragma unroll
    for (int nt = 0; nt < 4; ++nt) {
      int n = n0 + wn + 16 * nt + l15;
      size_t base = ((size_t)b * 2048 + n) * 512;
#pragma unroll
      for (int ot = 0; ot < 4; ++ot) {
        int o = o0 + wo + 16 * ot + 4 * quad;
        short4v pk;
#pragma unroll
        for (int r = 0; r < 4; ++r) pk[r] = bf16r(acc[ot][nt][r]);
        *(short4v*)&Yt[base + o] = pk;
      }
    }
  } else {  // EPI==2, V part
#pragma unroll
    for (int ot = 0; ot < 4; ++ot)
#pragma unroll
      for (int r = 0; r < 4; ++r) {
        int ch = o0 - 512 + wo + 16 * ot + 4 * quad + r;
#pragma unroll
        for (int nt = 0; nt < 4; ++nt)
          Yv[((size_t)b * 512 + ch) * 2048 + n0 + wn + 16 * nt + l15] =
              bf16r(acc[ot][nt][r]);
      }
  }
}

// ---------------------------------------------------------------------------
// Kernel 3: k2[b*8+h][m] = sum_d k~[m][h*64+d]^2 from bf16 kbT.
// Block 256 = 4 waves, one (b,m) row per wave.
// ---------------------------------------------------------------------------
__global__ __launch_bounds__(256) void k2_kernel(const short* __restrict__ kbT,
                                                 float* __restrict__ k2) {
  int w = threadIdx.x >> 6, l = threadIdx.x & 63;
  int row = blockIdx.x * 4 + w;  // row in [0, B*M)
  int b = row >> 11, m = row & 2047;
  short8 v = *(const short8*)&kbT[(size_t)row * 512 + 8 * l];
  float s = 0.f;
#pragma unroll
  for (int e = 0; e < 8; ++e) {
    float f = bf2f(v[e]);
    s += f * f;
  }
  s += __shfl_xor(s, 1);
  s += __shfl_xor(s, 2);
  s += __shfl_xor(s, 4);
  if ((l & 7) == 0) {
    int h = l >> 3;
    k2[((size_t)b * 8 + h) * 2048 + m] = s;
  }
}

// ---------------------------------------------------------------------------
// Kernel 4: L2-distance flash attention, all-bf16 MFMA, barrier-free j-loop.
// qb [b][n][512] bf16, kbT [b][m][512] bf16, vb [b][ch][m] bf16,
// k2 [b*8+h][m] fp32, mask [b][m] int -> attn_t [b][n][512] bf16.
// 1D grid 1024 (XCD-swizzled), block 256 = 4 waves; wave owns 16 q-rows.
// K/V fragments loaded directly from global (b128), P transposed via
// wave-private LDS rows.
// ---------------------------------------------------------------------------
__global__ __launch_bounds__(256, 4) void attn_kernel(
    const short* __restrict__ qb, const short* __restrict__ kbT,
    const short* __restrict__ vb, const float* __restrict__ k2,
    const int* __restrict__ mask, short* __restrict__ attn_t) {
  // swizzle: id = ((g>>3)*32 + i)*8 + (g&7)  => same (b,h) stays on one XCD
  const int bid = blockIdx.x;
  const int rr = bid & 7, qq = bid >> 3;
  const int iblk = qq & 31, g = ((qq >> 5) << 3) | rr;
  const int h = g & 7, b = g >> 3;
  const int i0 = iblk * 64;

  const int tid = threadIdx.x;
  const int w = tid >> 6, l = tid & 63, quad = l >> 4, l15 = l & 15;

  __shared__ __align__(16) short p_s[64][72];

  const short* qrow = qb + ((size_t)b * N_ + i0 + 16 * w + l15) * 512 + h * 64;
  const short* kbase = kbT + (size_t)b * M_ * 512 + h * 64;
  const short* vbase = vb + ((size_t)b * 512 + h * 64) * (size_t)M_;
  const float* k2b = k2 + ((size_t)b * 8 + h) * M_;
  const int* mb = mask + (size_t)b * M_;

  // Q fragments (A-layout) + q2 from the same bf16 values
  short8 qa[2];
  float q2p = 0.f;
#pragma unroll
  for (int kt = 0; kt < 2; ++kt) {
    qa[kt] = *(const short8*)&qrow[32 * kt + 8 * quad];
#pragma unroll
    for (int jj = 0; jj < 8; ++jj) {
      float f = bf2f(qa[kt][jj]);
      q2p += f * f;
    }
  }
  float q2row = q2p + __shfl_xor(q2p, 16);
  q2row += __shfl_xor(q2row, 32);
  float q2c[4];
#pragma unroll
  for (int r = 0; r < 4; ++r) q2c[r] = __shfl(q2row, 4 * quad + r);

  floatx4 accO[4];
#pragma unroll
  for (int dt = 0; dt < 4; ++dt)
#pragma unroll
    for (int r = 0; r < 4; ++r) accO[dt][r] = 0.f;
  float mrow[4], lrow[4];
#pragma unroll
  for (int r = 0; r < 4; ++r) {
    mrow[r] = NEG_MAX;
    lrow[r] = 0.f;
  }

  for (int j0 = 0; j0 < M_; j0 += 64) {
    // ---- S = Q K^T (bf16), direct global K fragments ----
    floatx4 s4[4];
#pragma unroll
    for (int jt = 0; jt < 4; ++jt) {
      const short* krow = kbase + (size_t)(j0 + 16 * jt + l15) * 512;
      short8 k0 = *(const short8*)&krow[8 * quad];
      short8 k1 = *(const short8*)&krow[32 + 8 * quad];
      floatx4 a;
#pragma unroll
      for (int r = 0; r < 4; ++r) a[r] = 0.f;
      a = __builtin_amdgcn_mfma_f32_16x16x32_bf16(qa[0], k0, a, 0, 0, 0);
      a = __builtin_amdgcn_mfma_f32_16x16x32_bf16(qa[1], k1, a, 0, 0, 0);
      s4[jt] = a;
    }

    // ---- sim = -0.125*sqrt(max(q2+k2-2qk,0)), masked ----
#pragma unroll
    for (int jt = 0; jt < 4; ++jt) {
      int col = j0 + 16 * jt + l15;
      float k2v = k2b[col];
      int mv = mb[col];
#pragma unroll
      for (int r = 0; r < 4; ++r) {
        float d2 = fmaxf(fmaf(-2.f, s4[jt][r], q2c[r] + k2v), 0.f);
        float sim = -0.125f * sqrtf(fmaxf(d2, 1e-12f));
        s4[jt][r] = mv ? sim : NEG_MAX;
      }
    }

    // ---- online softmax ----
    float rm[4];
#pragma unroll
    for (int r = 0; r < 4; ++r)
      rm[r] = fmaxf(fmaxf(s4[0][r], s4[1][r]), fmaxf(s4[2][r], s4[3][r]));
#pragma unroll
    for (int off = 1; off < 16; off <<= 1)
#pragma unroll
      for (int r = 0; r < 4; ++r) rm[r] = fmaxf(rm[r], __shfl_xor(rm[r], off));

    float alpha[4], lsum[4];
#pragma unroll
    for (int r = 0; r < 4; ++r) {
      float mn = fmaxf(mrow[r], rm[r]);
      alpha[r] = __expf(mrow[r] - mn);
      mrow[r] = mn;
      lsum[r] = 0.f;
    }
#pragma unroll
    for (int jt = 0; jt < 4; ++jt)
#pragma unroll
      for (int r = 0; r < 4; ++r) {
        float p = __expf(s4[jt][r] - mrow[r]);
        lsum[r] += p;
        p_s[16 * w + 4 * quad + r][16 * jt + l15] = bf16r(p);
      }
#pragma unroll
    for (int off = 1; off < 16; off <<= 1)
#pragma unroll
      for (int r = 0; r < 4; ++r) lsum[r] += __shfl_xor(lsum[r], off);
#pragma unroll
    for (int r = 0; r < 4; ++r) lrow[r] = lrow[r] * alpha[r] + lsum[r];
#pragma unroll
    for (int dt = 0; dt < 4; ++dt)
#pragma unroll
      for (int r = 0; r < 4; ++r) accO[dt][r] *= alpha[r];

    // ---- O += P V, direct global V fragments (wave-private p_s rows) ----
    short8 pa[2];
#pragma unroll
    for (int kt = 0; kt < 2; ++kt)
      pa[kt] = *(const short8*)&p_s[16 * w + l15][32 * kt + 8 * quad];
#pragma unroll
    for (int dt = 0; dt < 4; ++dt) {
      const short* vrow = vbase + (size_t)(16 * dt + l15) * M_ + j0;
#pragma unroll
      for (int kt = 0; kt < 2; ++kt) {
        short8 vf = *(const short8*)&vrow[32 * kt + 8 * quad];
        accO[dt] =
            __builtin_amdgcn_mfma_f32_16x16x32_bf16(pa[kt], vf, accO[dt], 0, 0, 0);
      }
    }
  }

  // epilogue: write bf16 [b][n][512] directly from C-layout
#pragma unroll
  for (int r = 0; r < 4; ++r) {
    float rl = 1.0f / lrow[r];
    size_t base = ((size_t)b * N_ + i0 + 16 * w + 4 * quad + r) * 512 + h * 64;
#pragma unroll
    for (int dt = 0; dt < 4; ++dt)
      attn_t[base + 16 * dt + l15] = bf16r(accO[dt][r] * rl);
  }
}

// ---------------------------------------------------------------------------
extern "C" void kernel_launch(void* const* d_in, const int* in_sizes, int n_in,
                              void* d_out, int out_size, void* d_ws,
                              size_t ws_size, hipStream_t stream) {
  const float* fmap = (const float*)d_in[0];
  const float* context = (const float*)d_in[1];
  const int* mask = (const int*)d_in[2];
  const float* gamma = (const float*)d_in[3];
  const float* gamma_ctx = (const float*)d_in[4];
  const float* Wq = (const float*)d_in[5];
  const float* Wkv = (const float*)d_in[6];
  const float* Wout = (const float*)d_in[7];
  float* out = (float*)d_out;

  char* ws = (char*)d_ws;
  short* fmap_t = (short*)ws;                       // 4*2048*256  = 4 MB
  short* ctx_t = fmap_t + 2097152;                  // 4 MB
  short* qb = ctx_t + 2097152;                      // 4*2048*512 = 8 MB
  short* kbT = qb + 4194304;                        // 8 MB
  short* vb = kbT + 4194304;                        // 8 MB
  short* attn_t = vb + 4194304;                     // 8 MB
  float* k2 = (float*)(attn_t + 4194304);           // 256 KB

  dim3 blk64x4(64, 4);
  colnorm_t_kernel<<<dim3(N_ / 64, B_), blk64x4, 0, stream>>>(fmap, fmap_t,
                                                              DIM_, N_, 16.0f);
  colnorm_t_kernel<<<dim3(M_ / 64, B_), blk64x4, 0, stream>>>(context, ctx_t,
                                                              DIM_, M_, 16.0f);
  gemm_mfma_kernel<1, true><<<dim3(16, 4, B_), 256, 0, stream>>>(
      Wq, gamma, fmap_t, nullptr, qb, nullptr, DIM_, DINNER_);
  gemm_mfma_kernel<2, true><<<dim3(16, 8, B_), 256, 0, stream>>>(
      Wkv, gamma_ctx, ctx_t, nullptr, kbT, vb, DIM_, 2 * DINNER_);
  k2_kernel<<<dim3(B_ * M_ / 4), 256, 0, stream>>>(kbT, k2);
  attn_kernel<<<dim3(1024), 256, 0, stream>>>(qb, kbT, vb, k2, mask, attn_t);
  gemm_mfma_kernel<0, false><<<dim3(16, 2, B_), 256, 0, stream>>>(
      Wout, nullptr, attn_t, out, nullptr, nullptr, DINNER_, DIM_);
}